// Round 17
// baseline (103.898 us; speedup 1.0000x reference)
//
#include <hip/hip_runtime.h>

// NCC loss, fused z-sweep, v17 = R15 (packed f32, ZC=40, T14 prefetch,
// literal ring, owner-yf) + two instruction-count cuts:
//  - xf-slide: 192 threads x 2 outputs (24 rows x 8 col-pair groups,
//    row-major lanes); slide state dies at barrier B -> no lag registers.
//  - paired stage: float2 global loads (pairs never straddle x-bounds since
//    x0 and 0/160 are even), one validity flag per pair.
// st stride 25 v2f (bank-spread for slide reads). Grid 800 x 256, LDS ~12.5KB.

typedef float v2f __attribute__((ext_vector_type(2)));
typedef float v4f __attribute__((ext_vector_type(4)));

#define TX 16
#define TY 16
#define ZC 40
#define PH 24          // TY+8
#define PW 24          // logical halo width
#define PWP 25         // st row stride in v2f (pad: slide-read bank spread)
#define XFP 16         // v4f row stride
#define NSTEP 48       // ZC+8
#define NN 160
#define NPLANE (160*160)

__global__ void ncc_zero_ws(float* ws) { ws[0] = 0.0f; }

__global__ __launch_bounds__(256)
void ncc_fused(const float* __restrict__ pred, const float* __restrict__ target,
               float* __restrict__ ws) {
  __shared__ v2f st[PH * PWP];         // staged (t,p)          4.8 KB
  __shared__ v4f xf4[PH * XFP];        // x-filt (t,p,t2,p2)    6.1 KB
  __shared__ float xf1[PH * XFP];      // x-filt tp             1.5 KB
  __shared__ float wsum[4];

  const int tid = threadIdx.x;
  const int tx = tid & 15;
  const int ty = tid >> 4;             // 0..15

  int b = blockIdx.x;
  const int xt = b % 10; b /= 10;
  const int yt = b % 10; b /= 10;
  const int zc = b % 4;  b /= 4;
  const int x0 = xt * TX, y0 = yt * TY, z0 = zc * ZC;
  const size_t bbase = (size_t)b * (size_t)NN * (size_t)NPLANE;

  // ---- hoisted stage geometry: 288 col-PAIRS (12/row); 2 strided slots ----
  // pair i: row = i/12, cp = i%12, gx = x0 + 2*cp - 4 (even -> never straddles)
  int poff0, poff1;        // global float-offset of pair base
  int pst0, pst1;          // st v2f address of pair base
  bool pv0, pv1;
  {
    const int row = tid / 12, cp = tid - row * 12;
    const int gy = y0 + row - 4, gx = x0 + 2 * cp - 4;
    pv0 = ((unsigned)gy < NN) && (gx >= 0) && (gx <= NN - 2);
    poff0 = gy * NN + gx;
    pst0 = row * PWP + 2 * cp;
  }
  {
    const int i = tid + 256;           // only tid < 32 has a second pair
    const int row = i / 12, cp = i - row * 12;
    const int gy = y0 + row - 4, gx = x0 + 2 * cp - 4;
    pv1 = (tid < 32) && ((unsigned)gy < NN) && (gx >= 0) && (gx <= NN - 2);
    poff1 = gy * NN + gx;
    pst1 = row * PWP + 2 * cp;
  }

  // ---- hoisted xf-slide geometry: 192 threads = 8 groups x 24 rows ----
  const int xf_g   = tid / 24;         // 0..7 (for tid<192)
  const int xf_row = tid - xf_g * 24;  // 0..23
  const int xf_rd  = xf_row * PWP + 2 * xf_g;   // st read base (taps +k)
  const int xf_wr  = xf_row * XFP + 2 * xf_g;   // xf write base

  float rt0, rp0, rt1, rp1;            // prefetch pair 0 (t,p for 2 x)
  float rt2, rp2, rt3, rp3;            // prefetch pair 1

#define PRELOAD(SS) do {                                                      \
    const int zi_ = z0 - 4 + (SS);                                            \
    if ((unsigned)zi_ < NN) {                                                 \
      const size_t zb_ = bbase + (size_t)zi_ * (size_t)NPLANE;                \
      if (pv0) {                                                              \
        const float2 t2_ = *(const float2*)(target + zb_ + poff0);            \
        const float2 p2_ = *(const float2*)(pred   + zb_ + poff0);            \
        rt0 = t2_.x; rt1 = t2_.y; rp0 = p2_.x; rp1 = p2_.y;                   \
      } else { rt0 = 0; rt1 = 0; rp0 = 0; rp1 = 0; }                          \
      if (pv1) {                                                              \
        const float2 t2_ = *(const float2*)(target + zb_ + poff1);            \
        const float2 p2_ = *(const float2*)(pred   + zb_ + poff1);            \
        rt2 = t2_.x; rt3 = t2_.y; rp2 = p2_.x; rp3 = p2_.y;                   \
      } else { rt2 = 0; rt3 = 0; rp2 = 0; rp3 = 0; }                          \
    }                                                                         \
  } while (0)

  v2f b01[9], b23[9];
  float b4[9];
  v2f run01 = {0.0f, 0.0f}, run23 = {0.0f, 0.0f};
  float run4 = 0.0f;
  #pragma unroll
  for (int j = 0; j < 9; ++j) {
    b01[j] = (v2f){0.0f, 0.0f}; b23[j] = (v2f){0.0f, 0.0f}; b4[j] = 0.0f;
  }
  float acc = 0.0f;
  const float inv_kvol = 1.0f / 729.0f;

  // ---- slice body; PP literal -> static ring indexing (rule #20) ----
#define ZBODY(PP) do {                                                        \
    const int s = s0 + (PP);                                                  \
    if (s < NSTEP) {                                                          \
      const int zi = z0 - 4 + s;                                              \
      const bool zvalid = ((unsigned)zi < NN);    /* block-uniform */         \
      v2f c01 = {0.0f, 0.0f}, c23 = {0.0f, 0.0f};                             \
      float c4 = 0.0f;                                                        \
      if (zvalid) {                                                           \
        v2f w_;                                                               \
        w_.x = rt0; w_.y = rp0; st[pst0] = w_;                                \
        w_.x = rt1; w_.y = rp1; st[pst0 + 1] = w_;                            \
        if (tid < 32) {                                                       \
          w_.x = rt2; w_.y = rp2; st[pst1] = w_;                              \
          w_.x = rt3; w_.y = rp3; st[pst1 + 1] = w_;                          \
        }                                                                     \
        __syncthreads();   /* A: st visible */                                \
        if (tid < 192) {                                                      \
          /* xf-slide: build 9-tap window, emit out0, slide +1, emit out1 */  \
          v2f m01 = {0.0f, 0.0f};                                             \
          v2f m23 = {0.0f, 0.0f};                                             \
          float s_tp = 0.0f;                                                  \
          _Pragma("unroll")                                                   \
          for (int k = 0; k < 9; ++k) {                                       \
            const v2f v = st[xf_rd + k];                                      \
            m01 += v;                                                         \
            m23 = __builtin_elementwise_fma(v, v, m23);                       \
            s_tp = fmaf(v.x, v.y, s_tp);                                      \
          }                                                                   \
          v4f o_; o_.x = m01.x; o_.y = m01.y; o_.z = m23.x; o_.w = m23.y;     \
          xf4[xf_wr] = o_;                                                    \
          xf1[xf_wr] = s_tp;                                                  \
          const v2f vo = st[xf_rd];                                           \
          const v2f vn = st[xf_rd + 9];                                       \
          m01 += vn - vo;                                                     \
          m23 = __builtin_elementwise_fma(vn, vn, m23);                       \
          m23 = __builtin_elementwise_fma(-vo, vo, m23);                      \
          s_tp = fmaf(vn.x, vn.y, s_tp);                                      \
          s_tp = fmaf(-vo.x, vo.y, s_tp);                                     \
          o_.x = m01.x; o_.y = m01.y; o_.z = m23.x; o_.w = m23.y;             \
          xf4[xf_wr + 1] = o_;                                                \
          xf1[xf_wr + 1] = s_tp;                                              \
        }                                                                     \
        __syncthreads();   /* B: xf visible; st reads done */                 \
      }                                                                       \
      /* T14: issue next slice's loads; complete during yf+ring+NCC */        \
      if (s + 1 < NSTEP) { PRELOAD(s + 1); }                                  \
      if (zvalid) {                                                           \
        v4f a4 = {0.0f, 0.0f, 0.0f, 0.0f};                                    \
        _Pragma("unroll")                                                     \
        for (int dy = 0; dy < 9; ++dy) {                                      \
          a4 += xf4[(ty + dy) * XFP + tx];                                    \
          c4 += xf1[(ty + dy) * XFP + tx];                                    \
        }                                                                     \
        c01.x = a4.x; c01.y = a4.y; c23.x = a4.z; c23.y = a4.w;               \
      }                                                                       \
      run01 += c01 - b01[(PP)]; b01[(PP)] = c01;                              \
      run23 += c23 - b23[(PP)]; b23[(PP)] = c23;                              \
      run4  += c4  - b4[(PP)];  b4[(PP)]  = c4;                               \
      if (s >= 8) {                                                           \
        const v2f avg = run01 * inv_kvol;                                     \
        const v2f var = __builtin_elementwise_fma(-avg, run01, run23);        \
        const float cross = fmaf(-avg.y, run01.x, run4);                      \
        acc += (cross * cross) / (var.x * var.y + 1e-5f);                     \
      }                                                                       \
    }                                                                         \
  } while (0)

  // ---- prologue: issue loads for slice 0 ----
  PRELOAD(0);

  // 48 slices: loop-of-9 (slot = s % 9 since stride 9)
  for (int s0 = 0; s0 < NSTEP; s0 += 9) {
    ZBODY(0); ZBODY(1); ZBODY(2); ZBODY(3); ZBODY(4);
    ZBODY(5); ZBODY(6); ZBODY(7); ZBODY(8);
  }
#undef ZBODY
#undef PRELOAD

  // ---- reduction: wave shuffle -> LDS -> one atomicAdd per block ----
  #pragma unroll
  for (int off = 32; off > 0; off >>= 1)
    acc += __shfl_down(acc, off, 64);
  if ((tid & 63) == 0) wsum[tid >> 6] = acc;
  __syncthreads();
  if (tid == 0) {
    float tot = wsum[0] + wsum[1] + wsum[2] + wsum[3];
    atomicAdd(ws, tot);
  }
}

__global__ void ncc_finalize(const float* __restrict__ ws, float* __restrict__ out) {
  out[0] = -ws[0] * (1.0f / 8192000.0f);
}

extern "C" void kernel_launch(void* const* d_in, const int* in_sizes, int n_in,
                              void* d_out, int out_size, void* d_ws, size_t ws_size,
                              hipStream_t stream) {
  const float* pred   = (const float*)d_in[0];
  const float* target = (const float*)d_in[1];
  float* out = (float*)d_out;
  float* ws  = (float*)d_ws;

  ncc_zero_ws<<<1, 1, 0, stream>>>(ws);
  // grid: 10 x-tiles * 10 y-tiles * 4 z-chunks * 2 batches = 800 blocks
  ncc_fused<<<800, 256, 0, stream>>>(pred, target, ws);
  ncc_finalize<<<1, 1, 0, stream>>>(ws, out);
}

// Round 18
// 94.526 us; speedup vs baseline: 1.0991x; 1.0991x over previous
//
#include <hip/hip_runtime.h>

// NCC loss, fused z-sweep, v18 = R15 (packed f32, ZC=40, T14 prefetch,
// literal ring, 2 barriers/slice) + row-pair pre-sums for the y-filter:
//  - xf phase: 192 threads, each computes xf for rows (2r, 2r+1) of its
//    column (18 b64 st reads, same total as R15) AND writes the pair sum
//    xp[r] = xf[2r]+xf[2r+1].
//  - owner yf: 4 pair reads + 1 single-row read (branchless parity
//    addressing) instead of 9 row reads. -44% owner DS bytes.
// Grid 800 x 256, LDS ~16.2 KB.

typedef float v2f __attribute__((ext_vector_type(2)));
typedef float v4f __attribute__((ext_vector_type(4)));

#define TX 16
#define TY 16
#define ZC 40
#define PH 24          // TY+8
#define PW 24          // TX+8
#define XFP 16         // v4f row stride
#define NSTEP 48       // ZC+8
#define NN 160
#define NPLANE (160*160)

__global__ void ncc_zero_ws(float* ws) { ws[0] = 0.0f; }

__global__ __launch_bounds__(256)
void ncc_fused(const float* __restrict__ pred, const float* __restrict__ target,
               float* __restrict__ ws) {
  __shared__ v2f st[PH * PW];          // staged (t,p)          4.6 KB
  __shared__ v4f xf4[PH * XFP];        // x-filt (t,p,t2,p2)    6.1 KB
  __shared__ float xf1[PH * XFP];      // x-filt tp             1.5 KB
  __shared__ v4f xp4[12 * XFP];        // row-pair sums (4 mom) 3.1 KB
  __shared__ float xp1[12 * XFP];      // row-pair sums tp      0.8 KB
  __shared__ float wsum[4];

  const int tid = threadIdx.x;
  const int tx = tid & 15;
  const int ty = tid >> 4;             // 0..15

  int b = blockIdx.x;
  const int xt = b % 10; b /= 10;
  const int yt = b % 10; b /= 10;
  const int zc = b % 4;  b /= 4;
  const int x0 = xt * TX, y0 = yt * TY, z0 = zc * ZC;
  const size_t bbase = (size_t)b * (size_t)NN * (size_t)NPLANE;

  // ---- hoisted z-invariant stage geometry (3 strided positions) ----
  int soff0, soff1, soff2;
  bool sv0, sv1, sv2;
  {
    const int yy = tid / PW, xx = tid - yy * PW;
    const int gy = y0 + yy - 4, gx = x0 + xx - 4;
    sv0 = ((unsigned)gy < NN) && ((unsigned)gx < NN);
    soff0 = gy * NN + gx;
  }
  {
    const int pos = tid + 256;
    const int yy = pos / PW, xx = pos - yy * PW;
    const int gy = y0 + yy - 4, gx = x0 + xx - 4;
    sv1 = ((unsigned)gy < NN) && ((unsigned)gx < NN);
    soff1 = gy * NN + gx;
  }
  {
    const int pos = tid + 512;
    const int yy = pos / PW, xx = pos - yy * PW;
    const int gy = y0 + yy - 4, gx = x0 + xx - 4;
    sv2 = (tid < 64) && ((unsigned)gy < NN) && ((unsigned)gx < NN);
    soff2 = gy * NN + gx;
  }

  // ---- hoisted xf row-pair geometry (192 threads: 12 pairs x 16 cols) ----
  const int xfr = tid >> 4;            // pair index 0..11 (for tid<192)
  const int xfc = tid & 15;            // column 0..15
  // ---- hoisted owner yf geometry (branchless parity) ----
  const int jbase = (ty + 1) >> 1;               // first pair index
  const int srow  = ty + (((ty & 1) ^ 1) << 3);  // even ty: ty+8; odd: ty

  float rt0, rp0, rt1, rp1, rt2, rp2;  // prefetch regs (named -> static)

#define PRELOAD(SS) do {                                                      \
    const int zi_ = z0 - 4 + (SS);                                            \
    if ((unsigned)zi_ < NN) {                                                 \
      const size_t zb_ = bbase + (size_t)zi_ * (size_t)NPLANE;                \
      rt0 = sv0 ? target[zb_ + soff0] : 0.0f;                                 \
      rp0 = sv0 ? pred[zb_ + soff0]   : 0.0f;                                 \
      rt1 = sv1 ? target[zb_ + soff1] : 0.0f;                                 \
      rp1 = sv1 ? pred[zb_ + soff1]   : 0.0f;                                 \
      rt2 = sv2 ? target[zb_ + soff2] : 0.0f;                                 \
      rp2 = sv2 ? pred[zb_ + soff2]   : 0.0f;                                 \
    }                                                                         \
  } while (0)

  // ---- 9-tap x-filter of row YY into (M01,M23,TP) accumulators ----
#define XFROW(YY, M01, M23, TP) do {                                          \
    _Pragma("unroll")                                                         \
    for (int dx = 0; dx < 9; ++dx) {                                          \
      const v2f v = st[(YY) * PW + xfc + dx];                                 \
      M01 += v;                                                               \
      M23 = __builtin_elementwise_fma(v, v, M23);                             \
      TP = fmaf(v.x, v.y, TP);                                                \
    }                                                                         \
  } while (0)

  v2f b01[9], b23[9];
  float b4[9];
  v2f run01 = {0.0f, 0.0f}, run23 = {0.0f, 0.0f};
  float run4 = 0.0f;
  #pragma unroll
  for (int j = 0; j < 9; ++j) {
    b01[j] = (v2f){0.0f, 0.0f}; b23[j] = (v2f){0.0f, 0.0f}; b4[j] = 0.0f;
  }
  float acc = 0.0f;
  const float inv_kvol = 1.0f / 729.0f;

  // ---- slice body; PP literal -> static ring indexing (rule #20) ----
#define ZBODY(PP) do {                                                        \
    const int s = s0 + (PP);                                                  \
    if (s < NSTEP) {                                                          \
      const int zi = z0 - 4 + s;                                              \
      const bool zvalid = ((unsigned)zi < NN);    /* block-uniform */         \
      v2f c01 = {0.0f, 0.0f}, c23 = {0.0f, 0.0f};                             \
      float c4 = 0.0f;                                                        \
      if (zvalid) {                                                           \
        v2f w_;                                                               \
        w_.x = rt0; w_.y = rp0; st[tid] = w_;                                 \
        w_.x = rt1; w_.y = rp1; st[tid + 256] = w_;                           \
        if (tid < 64) { w_.x = rt2; w_.y = rp2; st[tid + 512] = w_; }         \
        __syncthreads();   /* A: st visible */                                \
        if (tid < 192) {                                                      \
          /* rows 2*xfr and 2*xfr+1 of column xfc, plus their pair sum */     \
          v2f a01 = {0.0f, 0.0f}, a23 = {0.0f, 0.0f}; float atp = 0.0f;       \
          v2f q01 = {0.0f, 0.0f}, q23 = {0.0f, 0.0f}; float qtp = 0.0f;       \
          XFROW(2 * xfr,     a01, a23, atp);                                  \
          XFROW(2 * xfr + 1, q01, q23, qtp);                                  \
          v4f o_;                                                             \
          o_.x = a01.x; o_.y = a01.y; o_.z = a23.x; o_.w = a23.y;             \
          xf4[(2 * xfr) * XFP + xfc] = o_;                                    \
          xf1[(2 * xfr) * XFP + xfc] = atp;                                   \
          o_.x = q01.x; o_.y = q01.y; o_.z = q23.x; o_.w = q23.y;             \
          xf4[(2 * xfr + 1) * XFP + xfc] = o_;                                \
          xf1[(2 * xfr + 1) * XFP + xfc] = qtp;                               \
          a01 += q01; a23 += q23; atp += qtp;                                 \
          o_.x = a01.x; o_.y = a01.y; o_.z = a23.x; o_.w = a23.y;             \
          xp4[xfr * XFP + xfc] = o_;                                          \
          xp1[xfr * XFP + xfc] = atp;                                         \
        }                                                                     \
        __syncthreads();   /* B: xf/xp visible; st reads done */              \
      }                                                                       \
      /* T14: issue next slice's loads; complete during yf+ring+NCC */        \
      if (s + 1 < NSTEP) { PRELOAD(s + 1); }                                  \
      if (zvalid) {                                                           \
        /* owner yf: 1 single row + 4 pair sums (branchless parity) */        \
        v4f a4 = xf4[srow * XFP + tx];                                        \
        c4 = xf1[srow * XFP + tx];                                            \
        _Pragma("unroll")                                                     \
        for (int k = 0; k < 4; ++k) {                                         \
          a4 += xp4[(jbase + k) * XFP + tx];                                  \
          c4 += xp1[(jbase + k) * XFP + tx];                                  \
        }                                                                     \
        c01.x = a4.x; c01.y = a4.y; c23.x = a4.z; c23.y = a4.w;               \
      }                                                                       \
      run01 += c01 - b01[(PP)]; b01[(PP)] = c01;                              \
      run23 += c23 - b23[(PP)]; b23[(PP)] = c23;                              \
      run4  += c4  - b4[(PP)];  b4[(PP)]  = c4;                               \
      if (s >= 8) {                                                           \
        const v2f avg = run01 * inv_kvol;                                     \
        const v2f var = __builtin_elementwise_fma(-avg, run01, run23);        \
        const float cross = fmaf(-avg.y, run01.x, run4);                      \
        acc += (cross * cross) / (var.x * var.y + 1e-5f);                     \
      }                                                                       \
    }                                                                         \
  } while (0)

  // ---- prologue: issue loads for slice 0 ----
  PRELOAD(0);

  // 48 slices: loop-of-9 (slot = s % 9 since stride 9)
  for (int s0 = 0; s0 < NSTEP; s0 += 9) {
    ZBODY(0); ZBODY(1); ZBODY(2); ZBODY(3); ZBODY(4);
    ZBODY(5); ZBODY(6); ZBODY(7); ZBODY(8);
  }
#undef ZBODY
#undef XFROW
#undef PRELOAD

  // ---- reduction: wave shuffle -> LDS -> one atomicAdd per block ----
  #pragma unroll
  for (int off = 32; off > 0; off >>= 1)
    acc += __shfl_down(acc, off, 64);
  if ((tid & 63) == 0) wsum[tid >> 6] = acc;
  __syncthreads();
  if (tid == 0) {
    float tot = wsum[0] + wsum[1] + wsum[2] + wsum[3];
    atomicAdd(ws, tot);
  }
}

__global__ void ncc_finalize(const float* __restrict__ ws, float* __restrict__ out) {
  out[0] = -ws[0] * (1.0f / 8192000.0f);
}

extern "C" void kernel_launch(void* const* d_in, const int* in_sizes, int n_in,
                              void* d_out, int out_size, void* d_ws, size_t ws_size,
                              hipStream_t stream) {
  const float* pred   = (const float*)d_in[0];
  const float* target = (const float*)d_in[1];
  float* out = (float*)d_out;
  float* ws  = (float*)d_ws;

  ncc_zero_ws<<<1, 1, 0, stream>>>(ws);
  // grid: 10 x-tiles * 10 y-tiles * 4 z-chunks * 2 batches = 800 blocks
  ncc_fused<<<800, 256, 0, stream>>>(pred, target, ws);
  ncc_finalize<<<1, 1, 0, stream>>>(ws, out);
}

// Round 19
// 71.208 us; speedup vs baseline: 1.4591x; 1.3275x over previous
//
#include <hip/hip_runtime.h>

// NCC loss, fused z-sweep, v19 = R15 EXACT (packed f32, T14 prefetch,
// literal ring, 2 barriers/slice, 16x16 tile) with ZC=32 / 5 z-chunks:
// grid 800->1000 fixes CU load balance (critical-CU work 4x48 -> 4x40
// slice-units, -17%) at +4% total work. No register/LDS/phase changes.

typedef float v2f __attribute__((ext_vector_type(2)));
typedef float v4f __attribute__((ext_vector_type(4)));

#define TX 16
#define TY 16
#define ZC 32
#define PH 24          // TY+8
#define PW 24          // TX+8
#define XFP 16         // v4f row stride
#define NSTEP 40       // ZC+8
#define NN 160
#define NPLANE (160*160)

__global__ void ncc_zero_ws(float* ws) { ws[0] = 0.0f; }

__global__ __launch_bounds__(256)
void ncc_fused(const float* __restrict__ pred, const float* __restrict__ target,
               float* __restrict__ ws) {
  __shared__ v2f st[PH * PW];          // staged (t,p)          4.6 KB
  __shared__ v4f xf4[PH * XFP];        // x-filt (t,p,t2,p2)    6.1 KB
  __shared__ float xf1[PH * XFP];      // x-filt tp             1.5 KB
  __shared__ float wsum[4];

  const int tid = threadIdx.x;
  const int tx = tid & 15;
  const int ty = tid >> 4;             // 0..15

  int b = blockIdx.x;
  const int xt = b % 10; b /= 10;
  const int yt = b % 10; b /= 10;
  const int zc = b % 5;  b /= 5;
  const int x0 = xt * TX, y0 = yt * TY, z0 = zc * ZC;
  const size_t bbase = (size_t)b * (size_t)NN * (size_t)NPLANE;

  // ---- hoisted z-invariant stage geometry (3 strided positions) ----
  int soff0, soff1, soff2;
  bool sv0, sv1, sv2;
  {
    const int yy = tid / PW, xx = tid - yy * PW;
    const int gy = y0 + yy - 4, gx = x0 + xx - 4;
    sv0 = ((unsigned)gy < NN) && ((unsigned)gx < NN);
    soff0 = gy * NN + gx;
  }
  {
    const int pos = tid + 256;
    const int yy = pos / PW, xx = pos - yy * PW;
    const int gy = y0 + yy - 4, gx = x0 + xx - 4;
    sv1 = ((unsigned)gy < NN) && ((unsigned)gx < NN);
    soff1 = gy * NN + gx;
  }
  {
    const int pos = tid + 512;
    const int yy = pos / PW, xx = pos - yy * PW;
    const int gy = y0 + yy - 4, gx = x0 + xx - 4;
    sv2 = (tid < 64) && ((unsigned)gy < NN) && ((unsigned)gx < NN);
    soff2 = gy * NN + gx;
  }

  float rt0, rp0, rt1, rp1, rt2, rp2;  // prefetch regs (named -> static)

#define PRELOAD(SS) do {                                                      \
    const int zi_ = z0 - 4 + (SS);                                            \
    if ((unsigned)zi_ < NN) {                                                 \
      const size_t zb_ = bbase + (size_t)zi_ * (size_t)NPLANE;                \
      rt0 = sv0 ? target[zb_ + soff0] : 0.0f;                                 \
      rp0 = sv0 ? pred[zb_ + soff0]   : 0.0f;                                 \
      rt1 = sv1 ? target[zb_ + soff1] : 0.0f;                                 \
      rp1 = sv1 ? pred[zb_ + soff1]   : 0.0f;                                 \
      rt2 = sv2 ? target[zb_ + soff2] : 0.0f;                                 \
      rp2 = sv2 ? pred[zb_ + soff2]   : 0.0f;                                 \
    }                                                                         \
  } while (0)

  // ---- 9-tap x-filter, packed: pk_add + pk_fma + fma per tap ----
#define XFOUT(YY, XX) do {                                                    \
    v2f m01 = {0.0f, 0.0f};                                                   \
    v2f m23 = {0.0f, 0.0f};                                                   \
    float s_tp = 0.0f;                                                        \
    _Pragma("unroll")                                                         \
    for (int dx = 0; dx < 9; ++dx) {                                          \
      const v2f v = st[(YY) * PW + (XX) + dx];                                \
      m01 += v;                                                               \
      m23 = __builtin_elementwise_fma(v, v, m23);                             \
      s_tp = fmaf(v.x, v.y, s_tp);                                            \
    }                                                                         \
    v4f o_; o_.x = m01.x; o_.y = m01.y; o_.z = m23.x; o_.w = m23.y;           \
    xf4[(YY) * XFP + (XX)] = o_;                                              \
    xf1[(YY) * XFP + (XX)] = s_tp;                                            \
  } while (0)

  v2f b01[9], b23[9];
  float b4[9];
  v2f run01 = {0.0f, 0.0f}, run23 = {0.0f, 0.0f};
  float run4 = 0.0f;
  #pragma unroll
  for (int j = 0; j < 9; ++j) {
    b01[j] = (v2f){0.0f, 0.0f}; b23[j] = (v2f){0.0f, 0.0f}; b4[j] = 0.0f;
  }
  float acc = 0.0f;
  const float inv_kvol = 1.0f / 729.0f;

  // ---- slice body; PP literal -> static ring indexing (rule #20) ----
#define ZBODY(PP) do {                                                        \
    const int s = s0 + (PP);                                                  \
    if (s < NSTEP) {                                                          \
      const int zi = z0 - 4 + s;                                              \
      const bool zvalid = ((unsigned)zi < NN);    /* block-uniform */         \
      v2f c01 = {0.0f, 0.0f}, c23 = {0.0f, 0.0f};                             \
      float c4 = 0.0f;                                                        \
      if (zvalid) {                                                           \
        v2f w_;                                                               \
        w_.x = rt0; w_.y = rp0; st[tid] = w_;                                 \
        w_.x = rt1; w_.y = rp1; st[tid + 256] = w_;                           \
        if (tid < 64) { w_.x = rt2; w_.y = rp2; st[tid + 512] = w_; }         \
        __syncthreads();   /* A: st visible */                                \
        for (int pos = tid; pos < PH * TX; pos += 256) {                      \
          const int yy = pos >> 4;                                            \
          const int xx = pos & 15;                                            \
          XFOUT(yy, xx);                                                      \
        }                                                                     \
        __syncthreads();   /* B: xf visible; st reads done */                 \
      }                                                                       \
      /* T14: issue next slice's loads; complete during yf+ring+NCC */        \
      if (s + 1 < NSTEP) { PRELOAD(s + 1); }                                  \
      if (zvalid) {                                                           \
        v4f a4 = {0.0f, 0.0f, 0.0f, 0.0f};                                    \
        _Pragma("unroll")                                                     \
        for (int dy = 0; dy < 9; ++dy) {                                      \
          a4 += xf4[(ty + dy) * XFP + tx];        /* 2x v_pk_add_f32 */       \
          c4 += xf1[(ty + dy) * XFP + tx];                                    \
        }                                                                     \
        c01.x = a4.x; c01.y = a4.y; c23.x = a4.z; c23.y = a4.w;               \
      }                                                                       \
      run01 += c01 - b01[(PP)]; b01[(PP)] = c01;                              \
      run23 += c23 - b23[(PP)]; b23[(PP)] = c23;                              \
      run4  += c4  - b4[(PP)];  b4[(PP)]  = c4;                               \
      if (s >= 8) {                                                           \
        const v2f avg = run01 * inv_kvol;                                     \
        const v2f var = __builtin_elementwise_fma(-avg, run01, run23);        \
        const float cross = fmaf(-avg.y, run01.x, run4);                      \
        acc += (cross * cross) / (var.x * var.y + 1e-5f);                     \
      }                                                                       \
    }                                                                         \
  } while (0)

  // ---- prologue: issue loads for slice 0 ----
  PRELOAD(0);

  // 40 slices: loop-of-9 (slot = s % 9 since stride 9; guard trims tail)
  for (int s0 = 0; s0 < NSTEP; s0 += 9) {
    ZBODY(0); ZBODY(1); ZBODY(2); ZBODY(3); ZBODY(4);
    ZBODY(5); ZBODY(6); ZBODY(7); ZBODY(8);
  }
#undef ZBODY
#undef XFOUT
#undef PRELOAD

  // ---- reduction: wave shuffle -> LDS -> one atomicAdd per block ----
  #pragma unroll
  for (int off = 32; off > 0; off >>= 1)
    acc += __shfl_down(acc, off, 64);
  if ((tid & 63) == 0) wsum[tid >> 6] = acc;
  __syncthreads();
  if (tid == 0) {
    float tot = wsum[0] + wsum[1] + wsum[2] + wsum[3];
    atomicAdd(ws, tot);
  }
}

__global__ void ncc_finalize(const float* __restrict__ ws, float* __restrict__ out) {
  out[0] = -ws[0] * (1.0f / 8192000.0f);
}

extern "C" void kernel_launch(void* const* d_in, const int* in_sizes, int n_in,
                              void* d_out, int out_size, void* d_ws, size_t ws_size,
                              hipStream_t stream) {
  const float* pred   = (const float*)d_in[0];
  const float* target = (const float*)d_in[1];
  float* out = (float*)d_out;
  float* ws  = (float*)d_ws;

  ncc_zero_ws<<<1, 1, 0, stream>>>(ws);
  // grid: 10 x-tiles * 10 y-tiles * 5 z-chunks * 2 batches = 1000 blocks
  ncc_fused<<<1000, 256, 0, stream>>>(pred, target, ws);
  ncc_finalize<<<1, 1, 0, stream>>>(ws, out);
}